// Round 1
// 1118.803 us; speedup vs baseline: 1.0778x; 1.0778x over previous
//
#include <hip/hip_runtime.h>
#include <hip/hip_bf16.h>
#include <math.h>

#define HWD 262144   // 64*64*64

typedef __attribute__((ext_vector_type(8))) short bf16x8;   // 8 bf16 (4 VGPRs)
typedef __attribute__((ext_vector_type(16))) float f32x16;  // MFMA 32x32 accumulator

// ---------------- prep: weights -> bf16 GEMM layout A[ks 72][oc 128][kk 16]; w_map -> wmT ----
// K order: k = ((g*3+r)*3+s)*64 + z,  ks=k>>4, kk=k&15.
__global__ void k_prep(const float* __restrict__ w_t, const float* __restrict__ w_c,
                       const float* __restrict__ w_map,
                       __hip_bfloat16* __restrict__ A_t, __hip_bfloat16* __restrict__ A_c,
                       float* __restrict__ wmT) {
    int i = blockIdx.x * 256 + threadIdx.x;
    if (i < 147456) {
        int kk = i & 15, oc = (i >> 4) & 127, ks = i >> 11;
        int z4 = ks & 3, kq = ks >> 2;          // kq = (g*3+r)*3+s in [0,18)
        int g = kq / 9, tap = kq - 9 * g;       // tap = r*3+s
        int z = z4 * 16 + kk;
        // w_t (128,2,64,3,3): ((o*2+g)*64+kh)*9 + tap,  z=kh
        A_t[i] = __float2bfloat16(w_t[((oc * 2 + g) * 64 + z) * 9 + tap]);
        // w_c (128,2,3,3,64): ((o*2+g)*9+tap)*64 + kd,  z=kd
        A_c[i] = __float2bfloat16(w_c[((oc * 2 + g) * 9 + tap) * 64 + z]);
    }
    if (i < 8192) {
        wmT[i] = w_map[(i & 63) * 128 + (i >> 6)];   // wmT[k][c]
    }
}

__device__ inline void pack_row_bf16(__hip_bfloat16* dst, const float* src) {
    unsigned short u[16];
#pragma unroll
    for (int j = 0; j < 16; ++j) {
        __hip_bfloat16 h = __float2bfloat16(src[j]);
        u[j] = *reinterpret_cast<unsigned short*>(&h);
    }
    uint4* q = reinterpret_cast<uint4*>(dst);
    q[0] = *reinterpret_cast<const uint4*>(&u[0]);
    q[1] = *reinterpret_cast<const uint4*>(&u[8]);
}

// ---------------- transpose x (B,N,C) -> Xc bf16 [cg][h][w][d] ----------------
__global__ void k_trans_c(const float* __restrict__ x, __hip_bfloat16* __restrict__ Xc) {
    __shared__ float tile[64][65];
    int b = blockIdx.y;
    long n0 = (long)blockIdx.x * 64;
    int t = threadIdx.x;
    const float4* xp4 = (const float4*)(x + ((long)b * HWD + n0) * 64);
#pragma unroll
    for (int j = 0; j < 4; ++j) {
        int f4i = j * 256 + t;
        float4 v = xp4[f4i];
        int row = f4i >> 4;
        int c4 = (f4i & 15) * 4;
        tile[c4 + 0][row] = v.x;
        tile[c4 + 1][row] = v.y;
        tile[c4 + 2][row] = v.z;
        tile[c4 + 3][row] = v.w;
    }
    __syncthreads();
    int c = t >> 2, sub = t & 3;
    pack_row_bf16(Xc + (long)(b * 64 + c) * HWD + n0 + sub * 16, &tile[c][sub * 16]);
}

// ---------------- transpose x -> Xt bf16 [cg][w][d][h] ----------------
__global__ void k_trans_t(const float* __restrict__ x, __hip_bfloat16* __restrict__ Xt) {
    __shared__ float tile[64][65];   // [c][h]
    int b = blockIdx.y;
    int wd = blockIdx.x;             // w*64+d
    int t = threadIdx.x;
#pragma unroll
    for (int j = 0; j < 4; ++j) {
        int f4i = j * 256 + t;       // 64 h x 16 c-quads
        int h = f4i >> 4;
        int c4 = (f4i & 15) * 4;
        float4 v = *(const float4*)(x + ((long)b * HWD + (long)h * 4096 + wd) * 64 + c4);
        tile[c4 + 0][h] = v.x;
        tile[c4 + 1][h] = v.y;
        tile[c4 + 2][h] = v.z;
        tile[c4 + 3][h] = v.w;
    }
    __syncthreads();
    int c = t >> 2, sub = t & 3;
    pack_row_bf16(Xt + (long)(b * 64 + c) * HWD + (long)wd * 64 + sub * 16, &tile[c][sub * 16]);
}

// ---------------- unified MFMA conv: per (b,ch) GEMM C[128][4096] = A[128][1152] * B ----------
// B[k=(g,r,s,z)][n=(p,q)] = X[2ch+g][p+r-1][q+s-1][z]  (implicit im2col via address shifts)
// conv_t: X=Xt (p=w,q=d,z=kh) -> T[b][c][w2][w][d];  conv_c: X=Xc (p=h,q=w,z=kd) -> Cc[b][c][w2][h][w]
__global__ __launch_bounds__(256, 4) void k_conv_mfma(
        const __hip_bfloat16* __restrict__ X, const __hip_bfloat16* __restrict__ Aglob,
        const float* __restrict__ bias, float* __restrict__ Out) {
    int blk = blockIdx.x;
    int grp = blk >> 5;             // b*32+ch
    int pt = blk & 31;              // p-tile: 2 p-rows
    int b = grp >> 5, ch = grp & 31;
    int p0 = pt * 2;
    const __hip_bfloat16* Xg = X + ((long)(b * 64 + 2 * ch)) * HWD;
    int t = threadIdx.x;
    int lane = t & 63, wv = t >> 6;

    __shared__ short Asm[128 * 24];   // rows: 16 data bf16 + 8 pad = 48B
    __shared__ short Bsm[128 * 24];

    f32x16 acc00 = {0}, acc01 = {0}, acc10 = {0}, acc11 = {0};

    int srow = t >> 1, shalf = t & 1;     // staging: row 0..127, 16B half
    int pr = srow >> 6, q = srow & 63;    // B-row -> (p-row, q)
    int O0 = (wv >> 1) * 64;              // wave oc base
    int N0 = (wv & 1) * 64;               // wave n base
    int lrow = lane & 31, lq = lane >> 5;

    for (int ks = 0; ks < 72; ++ks) {
        int z4 = ks & 3, kq = ks >> 2;
        int g = kq / 9, tap = kq - 9 * g;
        int r = tap / 3, s = tap - 3 * r;
        // A stage: contiguous 4KB
        uint4 av = *(const uint4*)(Aglob + ks * 2048 + t * 8);
        // B stage: predicated 16B from X
        int pp = p0 + pr + r - 1, qq = q + s - 1;
        uint4 bv = {0u, 0u, 0u, 0u};
        if (pp >= 0 && pp < 64 && qq >= 0 && qq < 64)
            bv = *(const uint4*)(Xg + (long)g * HWD + ((pp << 6) + qq) * 64 + z4 * 16 + shalf * 8);
        __syncthreads();
        *(uint4*)(Asm + srow * 24 + shalf * 8) = av;
        *(uint4*)(Bsm + srow * 24 + shalf * 8) = bv;
        __syncthreads();
        bf16x8 a0 = *(const bf16x8*)(Asm + (O0 + lrow) * 24 + lq * 8);
        bf16x8 a1 = *(const bf16x8*)(Asm + (O0 + 32 + lrow) * 24 + lq * 8);
        bf16x8 b0 = *(const bf16x8*)(Bsm + (N0 + lrow) * 24 + lq * 8);
        bf16x8 b1 = *(const bf16x8*)(Bsm + (N0 + 32 + lrow) * 24 + lq * 8);
        acc00 = __builtin_amdgcn_mfma_f32_32x32x16_bf16(a0, b0, acc00, 0, 0, 0);
        acc01 = __builtin_amdgcn_mfma_f32_32x32x16_bf16(a0, b1, acc01, 0, 0, 0);
        acc10 = __builtin_amdgcn_mfma_f32_32x32x16_bf16(a1, b0, acc10, 0, 0, 0);
        acc11 = __builtin_amdgcn_mfma_f32_32x32x16_bf16(a1, b1, acc11, 0, 0, 0);
    }

    // store: C/D layout col=lane&31, row=(reg&3)+8*(reg>>2)+4*(lane>>5)
    long base0 = ((long)(b * 64 + 2 * ch)) * HWD + (long)p0 * 64;
    int n0l = N0 + lrow, n1l = N0 + 32 + lrow;
    long noff0 = (long)(n0l >> 6) * 64 + (n0l & 63);
    long noff1 = (long)(n1l >> 6) * 64 + (n1l & 63);
#pragma unroll
    for (int reg = 0; reg < 16; ++reg) {
        int row = (reg & 3) + 8 * (reg >> 2) + 4 * lq;
        int oc0 = O0 + row, oc1 = O0 + 32 + row;
        long cb0 = base0 + (long)(oc0 >> 6) * HWD + (long)(oc0 & 63) * 4096;
        long cb1 = base0 + (long)(oc1 >> 6) * HWD + (long)(oc1 & 63) * 4096;
        float bs0 = bias[oc0], bs1 = bias[oc1];
        Out[cb0 + noff0] = acc00[reg] + bs0;
        Out[cb0 + noff1] = acc01[reg] + bs0;
        Out[cb1 + noff0] = acc10[reg] + bs1;
        Out[cb1 + noff1] = acc11[reg] + bs1;
    }
}

// ---------------- attn: At[b,c,h,w2,d] = sum_w Cc[b,c,w2,h,w] * T[b,c,w2,w,d] (bf16 out) ----
__global__ void k_attn(const float* __restrict__ Cc, const float* __restrict__ T,
                       __hip_bfloat16* __restrict__ At) {
    __shared__ float As[64][65];
    __shared__ float Bs[64][64];
    int bc = blockIdx.x >> 6, w2 = blockIdx.x & 63;
    const float* Ap = Cc + ((long)bc * 64 + w2) * 4096;
    const float* Bp = T + ((long)bc * 64 + w2) * 4096;
    int t = threadIdx.x;
#pragma unroll
    for (int e0 = 0; e0 < 4096; e0 += 256) {
        int e = e0 + t;
        int r = e >> 6, q = e & 63;
        As[r][q] = Ap[e];
        Bs[r][q] = Bp[e];
    }
    __syncthreads();
    int h = t >> 2, dg = (t & 3) * 16;
    f32x16 acc = {0};
    for (int k = 0; k < 64; ++k) {
        float a = As[h][k];
#pragma unroll
        for (int i = 0; i < 16; ++i)
            acc[i] = fmaf(a, Bs[k][dg + i], acc[i]);
    }
    float tmp[16];
#pragma unroll
    for (int i = 0; i < 16; ++i) tmp[i] = acc[i];
    pack_row_bf16(At + (long)bc * HWD + (long)h * 4096 + w2 * 64 + dg, tmp);
}

// ---------------- f: F[b,c,h,w,d] = sum_w2 Cc[b,c,w2,h,w] * T[b,c,w2,w,d] (bf16 out) ----
__global__ void k_f(const float* __restrict__ Cc, const float* __restrict__ T,
                    __hip_bfloat16* __restrict__ F) {
    __shared__ float As[64][65];   // [h][w2]
    __shared__ float Bs[64][64];   // [w2][d]
    int bc = blockIdx.x >> 6, w = blockIdx.x & 63;
    const float* Ab = Cc + (long)bc * HWD;
    const float* Bb = T + (long)bc * HWD + w * 64;
    int t = threadIdx.x;
#pragma unroll
    for (int e0 = 0; e0 < 4096; e0 += 256) {
        int e = e0 + t;
        int w2 = e >> 6, q = e & 63;
        As[q][w2] = Ab[(long)w2 * 4096 + q * 64 + w];
        Bs[w2][q] = Bb[(long)w2 * 4096 + q];
    }
    __syncthreads();
    int h = t >> 2, dg = (t & 3) * 16;
    f32x16 acc = {0};
    for (int k = 0; k < 64; ++k) {
        float a = As[h][k];
#pragma unroll
        for (int i = 0; i < 16; ++i)
            acc[i] = fmaf(a, Bs[k][dg + i], acc[i]);
    }
    float tmp[16];
#pragma unroll
    for (int i = 0; i < 16; ++i) tmp[i] = acc[i];
    pack_row_bf16(F + (long)bc * HWD + (long)h * 4096 + w * 64 + dg, tmp);
}

// ---------------- map: out[b,n,c] = gelu( wm[c,:64].(x*F) + wm[c,64:].At + b_map[c] ) ------
// v2: LDS-staged x reads and out writes. Each 64B line of x is fetched by ONE float4
// instruction (4 lanes cover the line) and consumed immediately from LDS; each 64B line
// of out is produced by ONE float4 store. Kills the ~2.8x fetch / ~2.4x write HBM
// amplification seen in v1 (766MB fetch vs 268MB ideal).
// F/At reads stay direct: coalesced, single-use, 1x traffic already.
__global__ __launch_bounds__(256, 4) void k_map(const float* __restrict__ x,
        const __hip_bfloat16* __restrict__ F, const __hip_bfloat16* __restrict__ At,
        const float* __restrict__ wmT, const float* __restrict__ b_map,
        float* __restrict__ out) {
    __shared__ float xs[16][257];    // [chan-within-chunk][n] ; read xs[k2][t] is bank-conflict-free
    int t = threadIdx.x;
    long n0 = (long)blockIdx.x * 256;
    long n = n0 + t;
    int b = (int)(n >> 18);
    long nn = n & (HWD - 1);
    const __hip_bfloat16* fp = F + (long)b * 64 * HWD + nn;
    const __hip_bfloat16* ap = At + (long)b * 64 * HWD + nn;
    f32x16 A0, A1, A2, A3;
#pragma unroll
    for (int i = 0; i < 16; ++i) {
        A0[i] = b_map[i];
        A1[i] = b_map[16 + i];
        A2[i] = b_map[32 + i];
        A3[i] = b_map[48 + i];
    }
    for (int kc = 0; kc < 4; ++kc) {
        __syncthreads();   // previous chunk's readers done
#pragma unroll
        for (int i2 = 0; i2 < 4; ++i2) {
            int f = i2 * 256 + t;
            int nr = f >> 2, j4 = (f & 3) * 4;     // 4 lanes cover one full 64B line
            float4 v = *(const float4*)(x + (n0 + nr) * 64 + kc * 16 + j4);
            xs[j4 + 0][nr] = v.x;
            xs[j4 + 1][nr] = v.y;
            xs[j4 + 2][nr] = v.z;
            xs[j4 + 3][nr] = v.w;
        }
        __syncthreads();
        for (int k2 = 0; k2 < 16; ++k2) {
            int k = kc * 16 + k2;
            float sf = xs[k2][t] * __bfloat162float(fp[(long)k * HWD]);
            float av = __bfloat162float(ap[(long)k * HWD]);
            const float* w1 = wmT + k * 64;
            const float* w2 = wmT + 4096 + k * 64;
#pragma unroll
            for (int i = 0; i < 16; ++i) {
                A0[i] = fmaf(w1[i], sf, fmaf(w2[i], av, A0[i]));
                A1[i] = fmaf(w1[16 + i], sf, fmaf(w2[16 + i], av, A1[i]));
                A2[i] = fmaf(w1[32 + i], sf, fmaf(w2[32 + i], av, A2[i]));
                A3[i] = fmaf(w1[48 + i], sf, fmaf(w2[48 + i], av, A3[i]));
            }
        }
    }
    const float inv_sqrt2 = 0.70710678118654752440f;
#pragma unroll
    for (int i = 0; i < 16; ++i) {
        A0[i] = 0.5f * A0[i] * (1.f + erff(A0[i] * inv_sqrt2));
        A1[i] = 0.5f * A1[i] * (1.f + erff(A1[i] * inv_sqrt2));
        A2[i] = 0.5f * A2[i] * (1.f + erff(A2[i] * inv_sqrt2));
        A3[i] = 0.5f * A3[i] * (1.f + erff(A3[i] * inv_sqrt2));
    }
    // staged output: each 64B out line written by exactly one float4 store
#define STORE_CHUNK(ACC, OC)                                                      \
    __syncthreads();                                                              \
    _Pragma("unroll") for (int j = 0; j < 16; ++j) xs[j][t] = ACC[j];             \
    __syncthreads();                                                              \
    _Pragma("unroll") for (int i2 = 0; i2 < 4; ++i2) {                            \
        int f = i2 * 256 + t;                                                     \
        int nr = f >> 2, j4 = (f & 3) * 4;                                        \
        float4 v;                                                                 \
        v.x = xs[j4 + 0][nr];                                                     \
        v.y = xs[j4 + 1][nr];                                                     \
        v.z = xs[j4 + 2][nr];                                                     \
        v.w = xs[j4 + 3][nr];                                                     \
        *(float4*)(out + (n0 + nr) * 64 + (OC) * 16 + j4) = v;                    \
    }
    STORE_CHUNK(A0, 0)
    STORE_CHUNK(A1, 1)
    STORE_CHUNK(A2, 2)
    STORE_CHUNK(A3, 3)
#undef STORE_CHUNK
}

extern "C" void kernel_launch(void* const* d_in, const int* in_sizes, int n_in,
                              void* d_out, int out_size, void* d_ws, size_t ws_size,
                              hipStream_t stream) {
    const float* x     = (const float*)d_in[0];
    const float* w_t   = (const float*)d_in[1];
    const float* b_t   = (const float*)d_in[2];
    const float* w_c   = (const float*)d_in[3];
    const float* b_c   = (const float*)d_in[4];
    const float* w_map = (const float*)d_in[5];
    const float* b_map = (const float*)d_in[6];
    float* out = (float*)d_out;
    float* ws = (float*)d_ws;

    // ws layout (float offsets), ~269 MB total:
    //  [0,        16777216)  Xc bf16  (33.5M elem)  -> reused as At bf16 after conv_c
    //  [16777216, 33554432)  Xt bf16                -> reused as F bf16 after conv_t
    //  [33554432, 67108864)  T fp32
    //  [67108864, ...)       A_t bf16 (147456) | A_c bf16 (147456) | wmT f32 (8192)
    __hip_bfloat16* Xc = (__hip_bfloat16*)ws;
    __hip_bfloat16* Xt = (__hip_bfloat16*)(ws + 16777216L);
    float* T = ws + 33554432L;
    float* Cc = out;                                     // d_out as scratch
    __hip_bfloat16* A_t = (__hip_bfloat16*)(ws + 67108864L);
    __hip_bfloat16* A_c = (__hip_bfloat16*)(ws + 67182592L);
    float* wmT = ws + 67256320L;
    __hip_bfloat16* At_bf = Xc;                          // 67 MB, Xc dead after convs
    __hip_bfloat16* F_bf = Xt;                           // 67 MB, Xt dead after convs

    hipLaunchKernelGGL(k_prep, dim3(576), dim3(256), 0, stream, w_t, w_c, w_map, A_t, A_c, wmT);
    hipLaunchKernelGGL(k_trans_c, dim3(4096, 2), dim3(256), 0, stream, x, Xc);
    hipLaunchKernelGGL(k_trans_t, dim3(4096, 2), dim3(256), 0, stream, x, Xt);
    hipLaunchKernelGGL(k_conv_mfma, dim3(2048), dim3(256), 0, stream, Xt, A_t, b_t, T);
    hipLaunchKernelGGL(k_conv_mfma, dim3(2048), dim3(256), 0, stream, Xc, A_c, b_c, Cc);
    hipLaunchKernelGGL(k_attn, dim3(8192), dim3(256), 0, stream, Cc, T, At_bf);
    hipLaunchKernelGGL(k_f, dim3(8192), dim3(256), 0, stream, Cc, T, F_bf);
    hipLaunchKernelGGL(k_map, dim3(2048), dim3(256), 0, stream, x, F_bf, At_bf, wmT, b_map, out);
}

// Round 2
// 1087.881 us; speedup vs baseline: 1.1084x; 1.0284x over previous
//
#include <hip/hip_runtime.h>
#include <hip/hip_bf16.h>
#include <math.h>

#define HWD 262144   // 64*64*64

typedef __attribute__((ext_vector_type(8))) short bf16x8;   // 8 bf16 (4 VGPRs)
typedef __attribute__((ext_vector_type(16))) float f32x16;  // MFMA 32x32 accumulator

// ---------------- prep: weights -> bf16 GEMM layout A[ks 72][oc 128][kk 16]; w_map -> wmT ----
// K order: k = ((g*3+r)*3+s)*64 + z,  ks=k>>4, kk=k&15.
__global__ void k_prep(const float* __restrict__ w_t, const float* __restrict__ w_c,
                       const float* __restrict__ w_map,
                       __hip_bfloat16* __restrict__ A_t, __hip_bfloat16* __restrict__ A_c,
                       float* __restrict__ wmT) {
    int i = blockIdx.x * 256 + threadIdx.x;
    if (i < 147456) {
        int kk = i & 15, oc = (i >> 4) & 127, ks = i >> 11;
        int z4 = ks & 3, kq = ks >> 2;          // kq = (g*3+r)*3+s in [0,18)
        int g = kq / 9, tap = kq - 9 * g;       // tap = r*3+s
        int z = z4 * 16 + kk;
        // w_t (128,2,64,3,3): ((o*2+g)*64+kh)*9 + tap,  z=kh
        A_t[i] = __float2bfloat16(w_t[((oc * 2 + g) * 64 + z) * 9 + tap]);
        // w_c (128,2,3,3,64): ((o*2+g)*9+tap)*64 + kd,  z=kd
        A_c[i] = __float2bfloat16(w_c[((oc * 2 + g) * 9 + tap) * 64 + z]);
    }
    if (i < 8192) {
        wmT[i] = w_map[(i & 63) * 128 + (i >> 6)];   // wmT[k][c]
    }
}

__device__ inline void pack_row_bf16(__hip_bfloat16* dst, const float* src) {
    unsigned short u[16];
#pragma unroll
    for (int j = 0; j < 16; ++j) {
        __hip_bfloat16 h = __float2bfloat16(src[j]);
        u[j] = *reinterpret_cast<unsigned short*>(&h);
    }
    uint4* q = reinterpret_cast<uint4*>(dst);
    q[0] = *reinterpret_cast<const uint4*>(&u[0]);
    q[1] = *reinterpret_cast<const uint4*>(&u[8]);
}

// ---------------- transpose x (B,N,C) -> Xc bf16 [cg][h][w][d] ----------------
__global__ void k_trans_c(const float* __restrict__ x, __hip_bfloat16* __restrict__ Xc) {
    __shared__ float tile[64][65];
    int b = blockIdx.y;
    long n0 = (long)blockIdx.x * 64;
    int t = threadIdx.x;
    const float4* xp4 = (const float4*)(x + ((long)b * HWD + n0) * 64);
#pragma unroll
    for (int j = 0; j < 4; ++j) {
        int f4i = j * 256 + t;
        float4 v = xp4[f4i];
        int row = f4i >> 4;
        int c4 = (f4i & 15) * 4;
        tile[c4 + 0][row] = v.x;
        tile[c4 + 1][row] = v.y;
        tile[c4 + 2][row] = v.z;
        tile[c4 + 3][row] = v.w;
    }
    __syncthreads();
    int c = t >> 2, sub = t & 3;
    pack_row_bf16(Xc + (long)(b * 64 + c) * HWD + n0 + sub * 16, &tile[c][sub * 16]);
}

// ---------------- transpose x -> Xt bf16 [cg][w][d][h] ----------------
__global__ void k_trans_t(const float* __restrict__ x, __hip_bfloat16* __restrict__ Xt) {
    __shared__ float tile[64][65];   // [c][h]
    int b = blockIdx.y;
    int wd = blockIdx.x;             // w*64+d
    int t = threadIdx.x;
#pragma unroll
    for (int j = 0; j < 4; ++j) {
        int f4i = j * 256 + t;       // 64 h x 16 c-quads
        int h = f4i >> 4;
        int c4 = (f4i & 15) * 4;
        float4 v = *(const float4*)(x + ((long)b * HWD + (long)h * 4096 + wd) * 64 + c4);
        tile[c4 + 0][h] = v.x;
        tile[c4 + 1][h] = v.y;
        tile[c4 + 2][h] = v.z;
        tile[c4 + 3][h] = v.w;
    }
    __syncthreads();
    int c = t >> 2, sub = t & 3;
    pack_row_bf16(Xt + (long)(b * 64 + c) * HWD + (long)wd * 64 + sub * 16, &tile[c][sub * 16]);
}

// ---------------- unified MFMA conv: per (b,ch) GEMM C[128][4096] = A[128][1152] * B ----------
// B[k=(g,r,s,z)][n=(p,q)] = X[2ch+g][p+r-1][q+s-1][z]  (implicit im2col via address shifts)
// conv_t: X=Xt (p=w,q=d,z=kh) -> T[b][c][w2][w][d];  conv_c: X=Xc (p=h,q=w,z=kd) -> Cc[b][c][w2][h][w]
// XCD swizzle: all 32 pt-blocks of one grp land consecutively on one XCD (L2 reuse of X rows).
__global__ __launch_bounds__(256, 4) void k_conv_mfma(
        const __hip_bfloat16* __restrict__ X, const __hip_bfloat16* __restrict__ Aglob,
        const float* __restrict__ bias, float* __restrict__ Out) {
    int L = blockIdx.x;                       // 2048 = 64 grp * 32 pt
    int grp = (L & 7) * 8 + ((L >> 3) >> 5);  // XCD r handles grps [r*8, r*8+8)
    int pt = (L >> 3) & 31;
    int b = grp >> 5, ch = grp & 31;
    int p0 = pt * 2;
    const __hip_bfloat16* Xg = X + ((long)(b * 64 + 2 * ch)) * HWD;
    int t = threadIdx.x;
    int lane = t & 63, wv = t >> 6;

    __shared__ short Asm[128 * 24];   // rows: 16 data bf16 + 8 pad = 48B
    __shared__ short Bsm[128 * 24];

    f32x16 acc00 = {0}, acc01 = {0}, acc10 = {0}, acc11 = {0};

    int srow = t >> 1, shalf = t & 1;     // staging: row 0..127, 16B half
    int pr = srow >> 6, q = srow & 63;    // B-row -> (p-row, q)
    int O0 = (wv >> 1) * 64;              // wave oc base
    int N0 = (wv & 1) * 64;               // wave n base
    int lrow = lane & 31, lq = lane >> 5;

    for (int ks = 0; ks < 72; ++ks) {
        int z4 = ks & 3, kq = ks >> 2;
        int g = kq / 9, tap = kq - 9 * g;
        int r = tap / 3, s = tap - 3 * r;
        // A stage: contiguous 4KB
        uint4 av = *(const uint4*)(Aglob + ks * 2048 + t * 8);
        // B stage: predicated 16B from X
        int pp = p0 + pr + r - 1, qq = q + s - 1;
        uint4 bv = {0u, 0u, 0u, 0u};
        if (pp >= 0 && pp < 64 && qq >= 0 && qq < 64)
            bv = *(const uint4*)(Xg + (long)g * HWD + ((pp << 6) + qq) * 64 + z4 * 16 + shalf * 8);
        __syncthreads();
        *(uint4*)(Asm + srow * 24 + shalf * 8) = av;
        *(uint4*)(Bsm + srow * 24 + shalf * 8) = bv;
        __syncthreads();
        bf16x8 a0 = *(const bf16x8*)(Asm + (O0 + lrow) * 24 + lq * 8);
        bf16x8 a1 = *(const bf16x8*)(Asm + (O0 + 32 + lrow) * 24 + lq * 8);
        bf16x8 b0 = *(const bf16x8*)(Bsm + (N0 + lrow) * 24 + lq * 8);
        bf16x8 b1 = *(const bf16x8*)(Bsm + (N0 + 32 + lrow) * 24 + lq * 8);
        acc00 = __builtin_amdgcn_mfma_f32_32x32x16_bf16(a0, b0, acc00, 0, 0, 0);
        acc01 = __builtin_amdgcn_mfma_f32_32x32x16_bf16(a0, b1, acc01, 0, 0, 0);
        acc10 = __builtin_amdgcn_mfma_f32_32x32x16_bf16(a1, b0, acc10, 0, 0, 0);
        acc11 = __builtin_amdgcn_mfma_f32_32x32x16_bf16(a1, b1, acc11, 0, 0, 0);
    }

    // store: C/D layout col=lane&31, row=(reg&3)+8*(reg>>2)+4*(lane>>5)
    long base0 = ((long)(b * 64 + 2 * ch)) * HWD + (long)p0 * 64;
    int n0l = N0 + lrow, n1l = N0 + 32 + lrow;
    long noff0 = (long)(n0l >> 6) * 64 + (n0l & 63);
    long noff1 = (long)(n1l >> 6) * 64 + (n1l & 63);
#pragma unroll
    for (int reg = 0; reg < 16; ++reg) {
        int row = (reg & 3) + 8 * (reg >> 2) + 4 * lq;
        int oc0 = O0 + row, oc1 = O0 + 32 + row;
        long cb0 = base0 + (long)(oc0 >> 6) * HWD + (long)(oc0 & 63) * 4096;
        long cb1 = base0 + (long)(oc1 >> 6) * HWD + (long)(oc1 & 63) * 4096;
        float bs0 = bias[oc0], bs1 = bias[oc1];
        Out[cb0 + noff0] = acc00[reg] + bs0;
        Out[cb0 + noff1] = acc01[reg] + bs0;
        Out[cb1 + noff0] = acc10[reg] + bs1;
        Out[cb1 + noff1] = acc11[reg] + bs1;
    }
}

// ---------------- attn: At[b,c,h,w2,d] = sum_w Cc[b,c,w2,h,w] * T[b,c,w2,w,d] (bf16 out) ----
__global__ void k_attn(const float* __restrict__ Cc, const float* __restrict__ T,
                       __hip_bfloat16* __restrict__ At) {
    __shared__ float As[64][65];
    __shared__ float Bs[64][64];
    int bc = blockIdx.x >> 6, w2 = blockIdx.x & 63;
    const float* Ap = Cc + ((long)bc * 64 + w2) * 4096;
    const float* Bp = T + ((long)bc * 64 + w2) * 4096;
    int t = threadIdx.x;
#pragma unroll
    for (int e0 = 0; e0 < 4096; e0 += 256) {
        int e = e0 + t;
        int r = e >> 6, q = e & 63;
        As[r][q] = Ap[e];
        Bs[r][q] = Bp[e];
    }
    __syncthreads();
    int h = t >> 2, dg = (t & 3) * 16;
    f32x16 acc = {0};
    for (int k = 0; k < 64; ++k) {
        float a = As[h][k];
#pragma unroll
        for (int i = 0; i < 16; ++i)
            acc[i] = fmaf(a, Bs[k][dg + i], acc[i]);
    }
    float tmp[16];
#pragma unroll
    for (int i = 0; i < 16; ++i) tmp[i] = acc[i];
    pack_row_bf16(At + (long)bc * HWD + (long)h * 4096 + w2 * 64 + dg, tmp);
}

// ---------------- f: F[b,c,h,w,d] = sum_w2 Cc[b,c,w2,h,w] * T[b,c,w2,w,d] (bf16 out) ----
// XCD swizzle: all 64 w-blocks of one bc land consecutively on ONE XCD so the strided
// Cc column-gather (4B per 256B stride) is served from that XCD's L2 (1MB working set).
__global__ void k_f(const float* __restrict__ Cc, const float* __restrict__ T,
                    __hip_bfloat16* __restrict__ F) {
    __shared__ float As[64][65];   // [h][w2]
    __shared__ float Bs[64][64];   // [w2][d]
    int L = blockIdx.x;                        // 8192 = 128 bc * 64 w
    int bc = (L & 7) * 16 + ((L >> 3) >> 6);   // XCD r handles bc [r*16, r*16+16)
    int w = (L >> 3) & 63;
    const float* Ab = Cc + (long)bc * HWD;
    const float* Bb = T + (long)bc * HWD + w * 64;
    int t = threadIdx.x;
#pragma unroll
    for (int e0 = 0; e0 < 4096; e0 += 256) {
        int e = e0 + t;
        int w2 = e >> 6, q = e & 63;
        As[q][w2] = Ab[(long)w2 * 4096 + q * 64 + w];
        Bs[w2][q] = Bb[(long)w2 * 4096 + q];
    }
    __syncthreads();
    int h = t >> 2, dg = (t & 3) * 16;
    f32x16 acc = {0};
    for (int k = 0; k < 64; ++k) {
        float a = As[h][k];
#pragma unroll
        for (int i = 0; i < 16; ++i)
            acc[i] = fmaf(a, Bs[k][dg + i], acc[i]);
    }
    float tmp[16];
#pragma unroll
    for (int i = 0; i < 16; ++i) tmp[i] = acc[i];
    pack_row_bf16(F + (long)bc * HWD + (long)h * 4096 + w * 64 + dg, tmp);
}

// ---------------- map: out[b,n,c] = gelu( wm[c,:64].(x*F) + wm[c,64:].At + b_map[c] ) ------
// v3: ALL global traffic staged through LDS.
//  - x: full-64B-line float4 loads (as v2).
//  - F/At: 16-B uint4 loads (1KB/wave-instr) into LDS tiles, replacing 128 scalar 2-B
//    loads per thread (the v2 issue/latency bottleneck: VALUBusy 36%, 2 TB/s).
//  - out: staged 32 channels at a time; each 128-B line written by ONE wave instruction
//    (8 lanes x float4) -> kills the 2.0x write amplification (128-B dirty-granule).
__global__ __launch_bounds__(256, 4) void k_map(const float* __restrict__ x,
        const __hip_bfloat16* __restrict__ F, const __hip_bfloat16* __restrict__ At,
        const float* __restrict__ wmT, const float* __restrict__ b_map,
        float* __restrict__ out) {
    __shared__ char smem[33344];
    float (*xs)[257] = (float (*)[257])smem;                                   // [16][257]
    __hip_bfloat16 (*fs)[264] = (__hip_bfloat16 (*)[264])(smem + 16448);       // [16][264]
    __hip_bfloat16 (*as_)[264] = (__hip_bfloat16 (*)[264])(smem + 16448 + 8448);
    float (*os)[257] = (float (*)[257])smem;                                   // [32][257] reuse

    int t = threadIdx.x;
    long n0 = (long)blockIdx.x * 256;
    int b = (int)(n0 >> 18);
    long nn0 = n0 & (HWD - 1);
    const float* xblk = x + n0 * 64;
    const __hip_bfloat16* Fb = F + (long)b * 64 * HWD + nn0;
    const __hip_bfloat16* Ab = At + (long)b * 64 * HWD + nn0;

    f32x16 A0, A1, A2, A3;
#pragma unroll
    for (int i = 0; i < 16; ++i) {
        A0[i] = b_map[i];
        A1[i] = b_map[16 + i];
        A2[i] = b_map[32 + i];
        A3[i] = b_map[48 + i];
    }

    for (int kc = 0; kc < 4; ++kc) {
        __syncthreads();   // previous chunk's readers done
        // ---- stage x: each 64B line fetched by one float4 instruction (4 lanes/line)
#pragma unroll
        for (int i2 = 0; i2 < 4; ++i2) {
            int f = i2 * 256 + t;
            int nr = f >> 2, j4 = (f & 3) * 4;
            float4 v = *(const float4*)(xblk + nr * 64 + kc * 16 + j4);
            xs[j4 + 0][nr] = v.x;
            xs[j4 + 1][nr] = v.y;
            xs[j4 + 2][nr] = v.z;
            xs[j4 + 3][nr] = v.w;
        }
        // ---- stage F/At: 16 rows (channels) x 512B, uint4 loads, fully coalesced
#pragma unroll
        for (int it = 0; it < 2; ++it) {
            int idx = it * 256 + t;
            int row = idx >> 5, seg = idx & 31;
            long ga = (long)(kc * 16 + row) * HWD + seg * 8;
            *(uint4*)&fs[row][seg * 8] = *(const uint4*)(Fb + ga);
            *(uint4*)&as_[row][seg * 8] = *(const uint4*)(Ab + ga);
        }
        __syncthreads();
        for (int k2 = 0; k2 < 16; ++k2) {
            int k = kc * 16 + k2;
            float sf = xs[k2][t] * __bfloat162float(fs[k2][t]);
            float av = __bfloat162float(as_[k2][t]);
            const float* w1 = wmT + k * 64;
            const float* w2 = wmT + 4096 + k * 64;
#pragma unroll
            for (int i = 0; i < 16; ++i) {
                A0[i] = fmaf(w1[i], sf, fmaf(w2[i], av, A0[i]));
                A1[i] = fmaf(w1[16 + i], sf, fmaf(w2[16 + i], av, A1[i]));
                A2[i] = fmaf(w1[32 + i], sf, fmaf(w2[32 + i], av, A2[i]));
                A3[i] = fmaf(w1[48 + i], sf, fmaf(w2[48 + i], av, A3[i]));
            }
        }
    }
    const float inv_sqrt2 = 0.70710678118654752440f;
#pragma unroll
    for (int i = 0; i < 16; ++i) {
        A0[i] = 0.5f * A0[i] * (1.f + erff(A0[i] * inv_sqrt2));
        A1[i] = 0.5f * A1[i] * (1.f + erff(A1[i] * inv_sqrt2));
        A2[i] = 0.5f * A2[i] * (1.f + erff(A2[i] * inv_sqrt2));
        A3[i] = 0.5f * A3[i] * (1.f + erff(A3[i] * inv_sqrt2));
    }
    // ---- staged output: 32 channels (one full 128B line) per half, one float4 x 8 lanes
    // covers each 128B segment in a single instruction.
#define STORE_HALF(ACClo, ACChi, HALF)                                            \
    __syncthreads();                                                              \
    _Pragma("unroll") for (int j = 0; j < 16; ++j) {                              \
        os[j][t] = ACClo[j];                                                      \
        os[16 + j][t] = ACChi[j];                                                 \
    }                                                                             \
    __syncthreads();                                                              \
    _Pragma("unroll") for (int i2 = 0; i2 < 8; ++i2) {                            \
        int f = i2 * 256 + t;                                                     \
        int nr = f >> 3, c32 = (f & 7) * 4;                                       \
        float4 v;                                                                 \
        v.x = os[c32 + 0][nr];                                                    \
        v.y = os[c32 + 1][nr];                                                    \
        v.z = os[c32 + 2][nr];                                                    \
        v.w = os[c32 + 3][nr];                                                    \
        *(float4*)(out + (n0 + nr) * 64 + (HALF) * 32 + c32) = v;                 \
    }
    STORE_HALF(A0, A1, 0)
    STORE_HALF(A2, A3, 1)
#undef STORE_HALF
}

extern "C" void kernel_launch(void* const* d_in, const int* in_sizes, int n_in,
                              void* d_out, int out_size, void* d_ws, size_t ws_size,
                              hipStream_t stream) {
    const float* x     = (const float*)d_in[0];
    const float* w_t   = (const float*)d_in[1];
    const float* b_t   = (const float*)d_in[2];
    const float* w_c   = (const float*)d_in[3];
    const float* b_c   = (const float*)d_in[4];
    const float* w_map = (const float*)d_in[5];
    const float* b_map = (const float*)d_in[6];
    float* out = (float*)d_out;
    float* ws = (float*)d_ws;

    // ws layout (float offsets), ~269 MB total:
    //  [0,        16777216)  Xc bf16  (33.5M elem)  -> reused as At bf16 after conv_c
    //  [16777216, 33554432)  Xt bf16                -> reused as F bf16 after conv_t
    //  [33554432, 67108864)  T fp32
    //  [67108864, ...)       A_t bf16 (147456) | A_c bf16 (147456) | wmT f32 (8192)
    __hip_bfloat16* Xc = (__hip_bfloat16*)ws;
    __hip_bfloat16* Xt = (__hip_bfloat16*)(ws + 16777216L);
    float* T = ws + 33554432L;
    float* Cc = out;                                     // d_out as scratch
    __hip_bfloat16* A_t = (__hip_bfloat16*)(ws + 67108864L);
    __hip_bfloat16* A_c = (__hip_bfloat16*)(ws + 67182592L);
    float* wmT = ws + 67256320L;
    __hip_bfloat16* At_bf = Xc;                          // 67 MB, Xc dead after convs
    __hip_bfloat16* F_bf = Xt;                           // 67 MB, Xt dead after convs

    hipLaunchKernelGGL(k_prep, dim3(576), dim3(256), 0, stream, w_t, w_c, w_map, A_t, A_c, wmT);
    hipLaunchKernelGGL(k_trans_c, dim3(4096, 2), dim3(256), 0, stream, x, Xc);
    hipLaunchKernelGGL(k_trans_t, dim3(4096, 2), dim3(256), 0, stream, x, Xt);
    hipLaunchKernelGGL(k_conv_mfma, dim3(2048), dim3(256), 0, stream, Xt, A_t, b_t, T);
    hipLaunchKernelGGL(k_conv_mfma, dim3(2048), dim3(256), 0, stream, Xc, A_c, b_c, Cc);
    hipLaunchKernelGGL(k_attn, dim3(8192), dim3(256), 0, stream, Cc, T, At_bf);
    hipLaunchKernelGGL(k_f, dim3(8192), dim3(256), 0, stream, Cc, T, F_bf);
    hipLaunchKernelGGL(k_map, dim3(2048), dim3(256), 0, stream, x, F_bf, At_bf, wmT, b_map, out);
}

// Round 3
// 928.884 us; speedup vs baseline: 1.2982x; 1.1712x over previous
//
#include <hip/hip_runtime.h>
#include <hip/hip_bf16.h>
#include <math.h>

#define HWD 262144   // 64*64*64

typedef __attribute__((ext_vector_type(8))) short bf16x8;   // 8 bf16 (4 VGPRs)
typedef __attribute__((ext_vector_type(16))) float f32x16;  // MFMA 32x32 accumulator

// ---------------- prep: weights -> bf16 GEMM layout A[ks 72][oc 128][kk 16]; w_map -> wmT ----
// K order: k = ((g*3+r)*3+s)*64 + z,  ks=k>>4, kk=k&15.
__global__ void k_prep(const float* __restrict__ w_t, const float* __restrict__ w_c,
                       const float* __restrict__ w_map,
                       __hip_bfloat16* __restrict__ A_t, __hip_bfloat16* __restrict__ A_c,
                       float* __restrict__ wmT) {
    int i = blockIdx.x * 256 + threadIdx.x;
    if (i < 147456) {
        int kk = i & 15, oc = (i >> 4) & 127, ks = i >> 11;
        int z4 = ks & 3, kq = ks >> 2;          // kq = (g*3+r)*3+s in [0,18)
        int g = kq / 9, tap = kq - 9 * g;       // tap = r*3+s
        int z = z4 * 16 + kk;
        // w_t (128,2,64,3,3): ((o*2+g)*64+kh)*9 + tap,  z=kh
        A_t[i] = __float2bfloat16(w_t[((oc * 2 + g) * 64 + z) * 9 + tap]);
        // w_c (128,2,3,3,64): ((o*2+g)*9+tap)*64 + kd,  z=kd
        A_c[i] = __float2bfloat16(w_c[((oc * 2 + g) * 9 + tap) * 64 + z]);
    }
    if (i < 8192) {
        wmT[i] = w_map[(i & 63) * 128 + (i >> 6)];   // wmT[k][c]
    }
}

__device__ inline void pack_row_bf16(__hip_bfloat16* dst, const float* src) {
    unsigned short u[16];
#pragma unroll
    for (int j = 0; j < 16; ++j) {
        __hip_bfloat16 h = __float2bfloat16(src[j]);
        u[j] = *reinterpret_cast<unsigned short*>(&h);
    }
    uint4* q = reinterpret_cast<uint4*>(dst);
    q[0] = *reinterpret_cast<const uint4*>(&u[0]);
    q[1] = *reinterpret_cast<const uint4*>(&u[8]);
}

// ---------------- transpose x (B,N,C) -> Xc bf16 [cg][h][w][d] ----------------
__global__ void k_trans_c(const float* __restrict__ x, __hip_bfloat16* __restrict__ Xc) {
    __shared__ float tile[64][65];
    int b = blockIdx.y;
    long n0 = (long)blockIdx.x * 64;
    int t = threadIdx.x;
    const float4* xp4 = (const float4*)(x + ((long)b * HWD + n0) * 64);
#pragma unroll
    for (int j = 0; j < 4; ++j) {
        int f4i = j * 256 + t;
        float4 v = xp4[f4i];
        int row = f4i >> 4;
        int c4 = (f4i & 15) * 4;
        tile[c4 + 0][row] = v.x;
        tile[c4 + 1][row] = v.y;
        tile[c4 + 2][row] = v.z;
        tile[c4 + 3][row] = v.w;
    }
    __syncthreads();
    int c = t >> 2, sub = t & 3;
    pack_row_bf16(Xc + (long)(b * 64 + c) * HWD + n0 + sub * 16, &tile[c][sub * 16]);
}

// ---------------- transpose x -> Xt bf16 [cg][w][d][h] ----------------
__global__ void k_trans_t(const float* __restrict__ x, __hip_bfloat16* __restrict__ Xt) {
    __shared__ float tile[64][65];   // [c][h]
    int b = blockIdx.y;
    int wd = blockIdx.x;             // w*64+d
    int t = threadIdx.x;
#pragma unroll
    for (int j = 0; j < 4; ++j) {
        int f4i = j * 256 + t;       // 64 h x 16 c-quads
        int h = f4i >> 4;
        int c4 = (f4i & 15) * 4;
        float4 v = *(const float4*)(x + ((long)b * HWD + (long)h * 4096 + wd) * 64 + c4);
        tile[c4 + 0][h] = v.x;
        tile[c4 + 1][h] = v.y;
        tile[c4 + 2][h] = v.z;
        tile[c4 + 3][h] = v.w;
    }
    __syncthreads();
    int c = t >> 2, sub = t & 3;
    pack_row_bf16(Xt + (long)(b * 64 + c) * HWD + (long)wd * 64 + sub * 16, &tile[c][sub * 16]);
}

// ---------------- unified MFMA conv: per (b,ch) GEMM C[128][4096] = A[128][1152] * B ----------
// B[k=(g,r,s,z)][n=(p,q)] = X[2ch+g][p+r-1][q+s-1][z]  (implicit im2col via address shifts)
// conv_t: X=Xt (p=w,q=d,z=kh) -> T[b][c][w2][w][d];  conv_c: X=Xc (p=h,q=w,z=kd) -> Cc[b][c][w2][h][w]
// XCD swizzle: all 32 pt-blocks of one grp land consecutively on one XCD (L2 reuse of X rows).
__global__ __launch_bounds__(256, 4) void k_conv_mfma(
        const __hip_bfloat16* __restrict__ X, const __hip_bfloat16* __restrict__ Aglob,
        const float* __restrict__ bias, float* __restrict__ Out) {
    int L = blockIdx.x;                       // 2048 = 64 grp * 32 pt
    int grp = (L & 7) * 8 + ((L >> 3) >> 5);  // XCD r handles grps [r*8, r*8+8)
    int pt = (L >> 3) & 31;
    int b = grp >> 5, ch = grp & 31;
    int p0 = pt * 2;
    const __hip_bfloat16* Xg = X + ((long)(b * 64 + 2 * ch)) * HWD;
    int t = threadIdx.x;
    int lane = t & 63, wv = t >> 6;

    __shared__ short Asm[128 * 24];   // rows: 16 data bf16 + 8 pad = 48B
    __shared__ short Bsm[128 * 24];

    f32x16 acc00 = {0}, acc01 = {0}, acc10 = {0}, acc11 = {0};

    int srow = t >> 1, shalf = t & 1;     // staging: row 0..127, 16B half
    int pr = srow >> 6, q = srow & 63;    // B-row -> (p-row, q)
    int O0 = (wv >> 1) * 64;              // wave oc base
    int N0 = (wv & 1) * 64;               // wave n base
    int lrow = lane & 31, lq = lane >> 5;

    for (int ks = 0; ks < 72; ++ks) {
        int z4 = ks & 3, kq = ks >> 2;
        int g = kq / 9, tap = kq - 9 * g;
        int r = tap / 3, s = tap - 3 * r;
        // A stage: contiguous 4KB
        uint4 av = *(const uint4*)(Aglob + ks * 2048 + t * 8);
        // B stage: predicated 16B from X
        int pp = p0 + pr + r - 1, qq = q + s - 1;
        uint4 bv = {0u, 0u, 0u, 0u};
        if (pp >= 0 && pp < 64 && qq >= 0 && qq < 64)
            bv = *(const uint4*)(Xg + (long)g * HWD + ((pp << 6) + qq) * 64 + z4 * 16 + shalf * 8);
        __syncthreads();
        *(uint4*)(Asm + srow * 24 + shalf * 8) = av;
        *(uint4*)(Bsm + srow * 24 + shalf * 8) = bv;
        __syncthreads();
        bf16x8 a0 = *(const bf16x8*)(Asm + (O0 + lrow) * 24 + lq * 8);
        bf16x8 a1 = *(const bf16x8*)(Asm + (O0 + 32 + lrow) * 24 + lq * 8);
        bf16x8 b0 = *(const bf16x8*)(Bsm + (N0 + lrow) * 24 + lq * 8);
        bf16x8 b1 = *(const bf16x8*)(Bsm + (N0 + 32 + lrow) * 24 + lq * 8);
        acc00 = __builtin_amdgcn_mfma_f32_32x32x16_bf16(a0, b0, acc00, 0, 0, 0);
        acc01 = __builtin_amdgcn_mfma_f32_32x32x16_bf16(a0, b1, acc01, 0, 0, 0);
        acc10 = __builtin_amdgcn_mfma_f32_32x32x16_bf16(a1, b0, acc10, 0, 0, 0);
        acc11 = __builtin_amdgcn_mfma_f32_32x32x16_bf16(a1, b1, acc11, 0, 0, 0);
    }

    // store: C/D layout col=lane&31, row=(reg&3)+8*(reg>>2)+4*(lane>>5)
    long base0 = ((long)(b * 64 + 2 * ch)) * HWD + (long)p0 * 64;
    int n0l = N0 + lrow, n1l = N0 + 32 + lrow;
    long noff0 = (long)(n0l >> 6) * 64 + (n0l & 63);
    long noff1 = (long)(n1l >> 6) * 64 + (n1l & 63);
#pragma unroll
    for (int reg = 0; reg < 16; ++reg) {
        int row = (reg & 3) + 8 * (reg >> 2) + 4 * lq;
        int oc0 = O0 + row, oc1 = O0 + 32 + row;
        long cb0 = base0 + (long)(oc0 >> 6) * HWD + (long)(oc0 & 63) * 4096;
        long cb1 = base0 + (long)(oc1 >> 6) * HWD + (long)(oc1 & 63) * 4096;
        float bs0 = bias[oc0], bs1 = bias[oc1];
        Out[cb0 + noff0] = acc00[reg] + bs0;
        Out[cb0 + noff1] = acc01[reg] + bs0;
        Out[cb1 + noff0] = acc10[reg] + bs1;
        Out[cb1 + noff1] = acc11[reg] + bs1;
    }
}

// ---------------- attn: At[b,c,h,w2,d] = sum_w Cc[b,c,w2,h,w] * T[b,c,w2,w,d] (bf16 out) ----
__global__ void k_attn(const float* __restrict__ Cc, const float* __restrict__ T,
                       __hip_bfloat16* __restrict__ At) {
    __shared__ float As[64][65];
    __shared__ float Bs[64][64];
    int bc = blockIdx.x >> 6, w2 = blockIdx.x & 63;
    const float* Ap = Cc + ((long)bc * 64 + w2) * 4096;
    const float* Bp = T + ((long)bc * 64 + w2) * 4096;
    int t = threadIdx.x;
#pragma unroll
    for (int e0 = 0; e0 < 4096; e0 += 256) {
        int e = e0 + t;
        int r = e >> 6, q = e & 63;
        As[r][q] = Ap[e];
        Bs[r][q] = Bp[e];
    }
    __syncthreads();
    int h = t >> 2, dg = (t & 3) * 16;
    f32x16 acc = {0};
    for (int k = 0; k < 64; ++k) {
        float a = As[h][k];
#pragma unroll
        for (int i = 0; i < 16; ++i)
            acc[i] = fmaf(a, Bs[k][dg + i], acc[i]);
    }
    float tmp[16];
#pragma unroll
    for (int i = 0; i < 16; ++i) tmp[i] = acc[i];
    pack_row_bf16(At + (long)bc * HWD + (long)h * 4096 + w2 * 64 + dg, tmp);
}

// ---------------- f: F[b,c,h,w,d] = sum_w2 Cc[b,c,w2,h,w] * T[b,c,w2,w,d] (bf16 out) ----
// v2: block = (bc, 8-wide w-tile), 512 threads. Kills the v1 A-gather (4B/lane @ 256B
// stride, 64 lines/instr, 6% utilization -> 13% VALUBusy, 0.7 TB/s). A is now staged
// with float4 loads of 32B-contiguous Cc[w2][h][w0..w0+8) (50% line util); B fully
// coalesced. Bs rows padded to 68 floats: the 8-distinct-address broadcast read maps
// each w to its own bank quad (conflict-free). Thread = one (h,w) pair, 64 d accums.
// XCD swizzle: all 8 wt-blocks of one bc on one XCD (Cc/T L2-resident, ~2MB/bc).
__global__ __launch_bounds__(512, 4) void k_f(const float* __restrict__ Cc,
        const float* __restrict__ T, __hip_bfloat16* __restrict__ F) {
    __shared__ float As[16][64][8];   // [kk][h][w]        32 KB
    __shared__ float Bs[16][8][68];   // [kk][w][d(+pad)]  34 KB
    int L = blockIdx.x;               // 1024 = 128 bc * 8 wt
    int xcd = L & 7, j = L >> 3;      // j 0..127
    int bc = xcd * 16 + (j >> 3), wt = j & 7;
    const float* Ab = Cc + (long)bc * HWD + wt * 8;
    const float* Bb = T + (long)bc * HWD + wt * 8 * 64;
    int t = threadIdx.x;
    int w = t & 7, h = t >> 3;
    f32x16 acc0 = {0}, acc1 = {0}, acc2 = {0}, acc3 = {0};

    for (int w2c = 0; w2c < 4; ++w2c) {
        __syncthreads();
        // A stage: 16 kk x 64 h x 2 half-float4 (32B contiguous per (kk,h))
#pragma unroll
        for (int i = 0; i < 4; ++i) {
            int f = i * 512 + t;                       // 0..2047
            int half = f & 1, hh = (f >> 1) & 63, kk = f >> 7;
            float4 v = *(const float4*)(Ab + (long)(w2c * 16 + kk) * 4096 + hh * 64 + half * 4);
            *(float4*)&As[kk][hh][half * 4] = v;
        }
        // B stage: 16 kk x 8 w x 16 float4 (256B contiguous per (kk,w))
#pragma unroll
        for (int i = 0; i < 4; ++i) {
            int f = i * 512 + t;
            int d4 = f & 15, ww = (f >> 4) & 7, kk = f >> 7;
            float4 v = *(const float4*)(Bb + (long)(w2c * 16 + kk) * 4096 + ww * 64 + d4 * 4);
            *(float4*)&Bs[kk][ww][d4 * 4] = v;
        }
        __syncthreads();
        for (int kk = 0; kk < 16; ++kk) {
            float a = As[kk][h][w];
            const float* br = &Bs[kk][w][0];
#pragma unroll
            for (int i = 0; i < 16; ++i) {
                acc0[i] = fmaf(a, br[i], acc0[i]);
                acc1[i] = fmaf(a, br[16 + i], acc1[i]);
                acc2[i] = fmaf(a, br[32 + i], acc2[i]);
                acc3[i] = fmaf(a, br[48 + i], acc3[i]);
            }
        }
    }
    // store: F[bc][h][wt*8+w][d], 128B per thread (contiguous)
    __hip_bfloat16* Fp = F + (long)bc * HWD + (long)h * 4096 + (wt * 8 + w) * 64;
    float tmp[16];
#pragma unroll
    for (int i = 0; i < 16; ++i) tmp[i] = acc0[i];
    pack_row_bf16(Fp, tmp);
#pragma unroll
    for (int i = 0; i < 16; ++i) tmp[i] = acc1[i];
    pack_row_bf16(Fp + 16, tmp);
#pragma unroll
    for (int i = 0; i < 16; ++i) tmp[i] = acc2[i];
    pack_row_bf16(Fp + 32, tmp);
#pragma unroll
    for (int i = 0; i < 16; ++i) tmp[i] = acc3[i];
    pack_row_bf16(Fp + 48, tmp);
}

// ---------------- map: out[b,n,c] = gelu( wm[c,:64].(x*F) + wm[c,64:].At + b_map[c] ) ------
// v3: ALL global traffic staged through LDS.
//  - x: full-64B-line float4 loads (as v2).
//  - F/At: 16-B uint4 loads (1KB/wave-instr) into LDS tiles, replacing 128 scalar 2-B
//    loads per thread (the v2 issue/latency bottleneck: VALUBusy 36%, 2 TB/s).
//  - out: staged 32 channels at a time; each 128-B line written by ONE wave instruction
//    (8 lanes x float4) -> kills the 2.0x write amplification (128-B dirty-granule).
__global__ __launch_bounds__(256, 4) void k_map(const float* __restrict__ x,
        const __hip_bfloat16* __restrict__ F, const __hip_bfloat16* __restrict__ At,
        const float* __restrict__ wmT, const float* __restrict__ b_map,
        float* __restrict__ out) {
    __shared__ char smem[33344];
    float (*xs)[257] = (float (*)[257])smem;                                   // [16][257]
    __hip_bfloat16 (*fs)[264] = (__hip_bfloat16 (*)[264])(smem + 16448);       // [16][264]
    __hip_bfloat16 (*as_)[264] = (__hip_bfloat16 (*)[264])(smem + 16448 + 8448);
    float (*os)[257] = (float (*)[257])smem;                                   // [32][257] reuse

    int t = threadIdx.x;
    long n0 = (long)blockIdx.x * 256;
    int b = (int)(n0 >> 18);
    long nn0 = n0 & (HWD - 1);
    const float* xblk = x + n0 * 64;
    const __hip_bfloat16* Fb = F + (long)b * 64 * HWD + nn0;
    const __hip_bfloat16* Ab = At + (long)b * 64 * HWD + nn0;

    f32x16 A0, A1, A2, A3;
#pragma unroll
    for (int i = 0; i < 16; ++i) {
        A0[i] = b_map[i];
        A1[i] = b_map[16 + i];
        A2[i] = b_map[32 + i];
        A3[i] = b_map[48 + i];
    }

    for (int kc = 0; kc < 4; ++kc) {
        __syncthreads();   // previous chunk's readers done
        // ---- stage x: each 64B line fetched by one float4 instruction (4 lanes/line)
#pragma unroll
        for (int i2 = 0; i2 < 4; ++i2) {
            int f = i2 * 256 + t;
            int nr = f >> 2, j4 = (f & 3) * 4;
            float4 v = *(const float4*)(xblk + nr * 64 + kc * 16 + j4);
            xs[j4 + 0][nr] = v.x;
            xs[j4 + 1][nr] = v.y;
            xs[j4 + 2][nr] = v.z;
            xs[j4 + 3][nr] = v.w;
        }
        // ---- stage F/At: 16 rows (channels) x 512B, uint4 loads, fully coalesced
#pragma unroll
        for (int it = 0; it < 2; ++it) {
            int idx = it * 256 + t;
            int row = idx >> 5, seg = idx & 31;
            long ga = (long)(kc * 16 + row) * HWD + seg * 8;
            *(uint4*)&fs[row][seg * 8] = *(const uint4*)(Fb + ga);
            *(uint4*)&as_[row][seg * 8] = *(const uint4*)(Ab + ga);
        }
        __syncthreads();
        for (int k2 = 0; k2 < 16; ++k2) {
            int k = kc * 16 + k2;
            float sf = xs[k2][t] * __bfloat162float(fs[k2][t]);
            float av = __bfloat162float(as_[k2][t]);
            const float* w1 = wmT + k * 64;
            const float* w2 = wmT + 4096 + k * 64;
#pragma unroll
            for (int i = 0; i < 16; ++i) {
                A0[i] = fmaf(w1[i], sf, fmaf(w2[i], av, A0[i]));
                A1[i] = fmaf(w1[16 + i], sf, fmaf(w2[16 + i], av, A1[i]));
                A2[i] = fmaf(w1[32 + i], sf, fmaf(w2[32 + i], av, A2[i]));
                A3[i] = fmaf(w1[48 + i], sf, fmaf(w2[48 + i], av, A3[i]));
            }
        }
    }
    const float inv_sqrt2 = 0.70710678118654752440f;
#pragma unroll
    for (int i = 0; i < 16; ++i) {
        A0[i] = 0.5f * A0[i] * (1.f + erff(A0[i] * inv_sqrt2));
        A1[i] = 0.5f * A1[i] * (1.f + erff(A1[i] * inv_sqrt2));
        A2[i] = 0.5f * A2[i] * (1.f + erff(A2[i] * inv_sqrt2));
        A3[i] = 0.5f * A3[i] * (1.f + erff(A3[i] * inv_sqrt2));
    }
    // ---- staged output: 32 channels (one full 128B line) per half, one float4 x 8 lanes
    // covers each 128B segment in a single instruction.
#define STORE_HALF(ACClo, ACChi, HALF)                                            \
    __syncthreads();                                                              \
    _Pragma("unroll") for (int j = 0; j < 16; ++j) {                              \
        os[j][t] = ACClo[j];                                                      \
        os[16 + j][t] = ACChi[j];                                                 \
    }                                                                             \
    __syncthreads();                                                              \
    _Pragma("unroll") for (int i2 = 0; i2 < 8; ++i2) {                            \
        int f = i2 * 256 + t;                                                     \
        int nr = f >> 3, c32 = (f & 7) * 4;                                       \
        float4 v;                                                                 \
        v.x = os[c32 + 0][nr];                                                    \
        v.y = os[c32 + 1][nr];                                                    \
        v.z = os[c32 + 2][nr];                                                    \
        v.w = os[c32 + 3][nr];                                                    \
        *(float4*)(out + (n0 + nr) * 64 + (HALF) * 32 + c32) = v;                 \
    }
    STORE_HALF(A0, A1, 0)
    STORE_HALF(A2, A3, 1)
#undef STORE_HALF
}

extern "C" void kernel_launch(void* const* d_in, const int* in_sizes, int n_in,
                              void* d_out, int out_size, void* d_ws, size_t ws_size,
                              hipStream_t stream) {
    const float* x     = (const float*)d_in[0];
    const float* w_t   = (const float*)d_in[1];
    const float* b_t   = (const float*)d_in[2];
    const float* w_c   = (const float*)d_in[3];
    const float* b_c   = (const float*)d_in[4];
    const float* w_map = (const float*)d_in[5];
    const float* b_map = (const float*)d_in[6];
    float* out = (float*)d_out;
    float* ws = (float*)d_ws;

    // ws layout (float offsets), ~269 MB total:
    //  [0,        16777216)  Xc bf16  (33.5M elem)  -> reused as At bf16 after conv_c
    //  [16777216, 33554432)  Xt bf16                -> reused as F bf16 after conv_t
    //  [33554432, 67108864)  T fp32
    //  [67108864, ...)       A_t bf16 (147456) | A_c bf16 (147456) | wmT f32 (8192)
    __hip_bfloat16* Xc = (__hip_bfloat16*)ws;
    __hip_bfloat16* Xt = (__hip_bfloat16*)(ws + 16777216L);
    float* T = ws + 33554432L;
    float* Cc = out;                                     // d_out as scratch
    __hip_bfloat16* A_t = (__hip_bfloat16*)(ws + 67108864L);
    __hip_bfloat16* A_c = (__hip_bfloat16*)(ws + 67182592L);
    float* wmT = ws + 67256320L;
    __hip_bfloat16* At_bf = Xc;                          // 67 MB, Xc dead after convs
    __hip_bfloat16* F_bf = Xt;                           // 67 MB, Xt dead after convs

    hipLaunchKernelGGL(k_prep, dim3(576), dim3(256), 0, stream, w_t, w_c, w_map, A_t, A_c, wmT);
    hipLaunchKernelGGL(k_trans_c, dim3(4096, 2), dim3(256), 0, stream, x, Xc);
    hipLaunchKernelGGL(k_trans_t, dim3(4096, 2), dim3(256), 0, stream, x, Xt);
    hipLaunchKernelGGL(k_conv_mfma, dim3(2048), dim3(256), 0, stream, Xt, A_t, b_t, T);
    hipLaunchKernelGGL(k_conv_mfma, dim3(2048), dim3(256), 0, stream, Xc, A_c, b_c, Cc);
    hipLaunchKernelGGL(k_attn, dim3(8192), dim3(256), 0, stream, Cc, T, At_bf);
    hipLaunchKernelGGL(k_f, dim3(1024), dim3(512), 0, stream, Cc, T, F_bf);
    hipLaunchKernelGGL(k_map, dim3(2048), dim3(256), 0, stream, x, F_bf, At_bf, wmT, b_map, out);
}

// Round 4
// 799.572 us; speedup vs baseline: 1.5081x; 1.1617x over previous
//
#include <hip/hip_runtime.h>
#include <hip/hip_bf16.h>
#include <math.h>

#define HWD 262144   // 64*64*64

typedef __attribute__((ext_vector_type(8))) short bf16x8;   // 8 bf16 (4 VGPRs)
typedef __attribute__((ext_vector_type(16))) float f32x16;  // MFMA 32x32 accumulator

// ---------------- prep: weights -> bf16 GEMM layout A[ks 72][oc 128][kk 16]; w_map -> Wb bf16 ----
// K order: k = ((g*3+r)*3+s)*64 + z,  ks=k>>4, kk=k&15.
__global__ void k_prep(const float* __restrict__ w_t, const float* __restrict__ w_c,
                       const float* __restrict__ w_map,
                       __hip_bfloat16* __restrict__ A_t, __hip_bfloat16* __restrict__ A_c,
                       __hip_bfloat16* __restrict__ Wb) {
    int i = blockIdx.x * 256 + threadIdx.x;
    if (i < 147456) {
        int kk = i & 15, oc = (i >> 4) & 127, ks = i >> 11;
        int z4 = ks & 3, kq = ks >> 2;          // kq = (g*3+r)*3+s in [0,18)
        int g = kq / 9, tap = kq - 9 * g;       // tap = r*3+s
        int z = z4 * 16 + kk;
        // w_t (128,2,64,3,3): ((o*2+g)*64+kh)*9 + tap,  z=kh
        A_t[i] = __float2bfloat16(w_t[((oc * 2 + g) * 64 + z) * 9 + tap]);
        // w_c (128,2,3,3,64): ((o*2+g)*9+tap)*64 + kd,  z=kd
        A_c[i] = __float2bfloat16(w_c[((oc * 2 + g) * 9 + tap) * 64 + z]);
    }
    if (i < 8192) {
        Wb[i] = __float2bfloat16(w_map[i]);   // w_map is (C,2C) row-major = [c][k]
    }
}

__device__ inline void pack_row_bf16(__hip_bfloat16* dst, const float* src) {
    unsigned short u[16];
#pragma unroll
    for (int j = 0; j < 16; ++j) {
        __hip_bfloat16 h = __float2bfloat16(src[j]);
        u[j] = *reinterpret_cast<unsigned short*>(&h);
    }
    uint4* q = reinterpret_cast<uint4*>(dst);
    q[0] = *reinterpret_cast<const uint4*>(&u[0]);
    q[1] = *reinterpret_cast<const uint4*>(&u[8]);
}

// ---------------- transpose x (B,N,C) -> Xc bf16 [cg][h][w][d] ----------------
__global__ void k_trans_c(const float* __restrict__ x, __hip_bfloat16* __restrict__ Xc) {
    __shared__ float tile[64][65];
    int b = blockIdx.y;
    long n0 = (long)blockIdx.x * 64;
    int t = threadIdx.x;
    const float4* xp4 = (const float4*)(x + ((long)b * HWD + n0) * 64);
#pragma unroll
    for (int j = 0; j < 4; ++j) {
        int f4i = j * 256 + t;
        float4 v = xp4[f4i];
        int row = f4i >> 4;
        int c4 = (f4i & 15) * 4;
        tile[c4 + 0][row] = v.x;
        tile[c4 + 1][row] = v.y;
        tile[c4 + 2][row] = v.z;
        tile[c4 + 3][row] = v.w;
    }
    __syncthreads();
    int c = t >> 2, sub = t & 3;
    pack_row_bf16(Xc + (long)(b * 64 + c) * HWD + n0 + sub * 16, &tile[c][sub * 16]);
}

// ---------------- transpose x -> Xt bf16 [cg][w][d][h] ----------------
__global__ void k_trans_t(const float* __restrict__ x, __hip_bfloat16* __restrict__ Xt) {
    __shared__ float tile[64][65];   // [c][h]
    int b = blockIdx.y;
    int wd = blockIdx.x;             // w*64+d
    int t = threadIdx.x;
#pragma unroll
    for (int j = 0; j < 4; ++j) {
        int f4i = j * 256 + t;       // 64 h x 16 c-quads
        int h = f4i >> 4;
        int c4 = (f4i & 15) * 4;
        float4 v = *(const float4*)(x + ((long)b * HWD + (long)h * 4096 + wd) * 64 + c4);
        tile[c4 + 0][h] = v.x;
        tile[c4 + 1][h] = v.y;
        tile[c4 + 2][h] = v.z;
        tile[c4 + 3][h] = v.w;
    }
    __syncthreads();
    int c = t >> 2, sub = t & 3;
    pack_row_bf16(Xt + (long)(b * 64 + c) * HWD + (long)wd * 64 + sub * 16, &tile[c][sub * 16]);
}

// ---------------- unified MFMA conv: per (b,ch) GEMM C[128][4096] = A[128][1152] * B ----------
// B[k=(g,r,s,z)][n=(p,q)] = X[2ch+g][p+r-1][q+s-1][z]  (implicit im2col via address shifts)
// conv_t: X=Xt (p=w,q=d,z=kh) -> T[b][c][w2][w][d];  conv_c: X=Xc (p=h,q=w,z=kd) -> Cc[b][c][w2][h][w]
// XCD swizzle: all 32 pt-blocks of one grp land consecutively on one XCD (L2 reuse of X rows).
__global__ __launch_bounds__(256, 4) void k_conv_mfma(
        const __hip_bfloat16* __restrict__ X, const __hip_bfloat16* __restrict__ Aglob,
        const float* __restrict__ bias, float* __restrict__ Out) {
    int L = blockIdx.x;                       // 2048 = 64 grp * 32 pt
    int grp = (L & 7) * 8 + ((L >> 3) >> 5);  // XCD r handles grps [r*8, r*8+8)
    int pt = (L >> 3) & 31;
    int b = grp >> 5, ch = grp & 31;
    int p0 = pt * 2;
    const __hip_bfloat16* Xg = X + ((long)(b * 64 + 2 * ch)) * HWD;
    int t = threadIdx.x;
    int lane = t & 63, wv = t >> 6;

    __shared__ short Asm[128 * 24];   // rows: 16 data bf16 + 8 pad = 48B
    __shared__ short Bsm[128 * 24];

    f32x16 acc00 = {0}, acc01 = {0}, acc10 = {0}, acc11 = {0};

    int srow = t >> 1, shalf = t & 1;     // staging: row 0..127, 16B half
    int pr = srow >> 6, q = srow & 63;    // B-row -> (p-row, q)
    int O0 = (wv >> 1) * 64;              // wave oc base
    int N0 = (wv & 1) * 64;               // wave n base
    int lrow = lane & 31, lq = lane >> 5;

    for (int ks = 0; ks < 72; ++ks) {
        int z4 = ks & 3, kq = ks >> 2;
        int g = kq / 9, tap = kq - 9 * g;
        int r = tap / 3, s = tap - 3 * r;
        // A stage: contiguous 4KB
        uint4 av = *(const uint4*)(Aglob + ks * 2048 + t * 8);
        // B stage: predicated 16B from X
        int pp = p0 + pr + r - 1, qq = q + s - 1;
        uint4 bv = {0u, 0u, 0u, 0u};
        if (pp >= 0 && pp < 64 && qq >= 0 && qq < 64)
            bv = *(const uint4*)(Xg + (long)g * HWD + ((pp << 6) + qq) * 64 + z4 * 16 + shalf * 8);
        __syncthreads();
        *(uint4*)(Asm + srow * 24 + shalf * 8) = av;
        *(uint4*)(Bsm + srow * 24 + shalf * 8) = bv;
        __syncthreads();
        bf16x8 a0 = *(const bf16x8*)(Asm + (O0 + lrow) * 24 + lq * 8);
        bf16x8 a1 = *(const bf16x8*)(Asm + (O0 + 32 + lrow) * 24 + lq * 8);
        bf16x8 b0 = *(const bf16x8*)(Bsm + (N0 + lrow) * 24 + lq * 8);
        bf16x8 b1 = *(const bf16x8*)(Bsm + (N0 + 32 + lrow) * 24 + lq * 8);
        acc00 = __builtin_amdgcn_mfma_f32_32x32x16_bf16(a0, b0, acc00, 0, 0, 0);
        acc01 = __builtin_amdgcn_mfma_f32_32x32x16_bf16(a0, b1, acc01, 0, 0, 0);
        acc10 = __builtin_amdgcn_mfma_f32_32x32x16_bf16(a1, b0, acc10, 0, 0, 0);
        acc11 = __builtin_amdgcn_mfma_f32_32x32x16_bf16(a1, b1, acc11, 0, 0, 0);
    }

    // store: C/D layout col=lane&31, row=(reg&3)+8*(reg>>2)+4*(lane>>5)
    long base0 = ((long)(b * 64 + 2 * ch)) * HWD + (long)p0 * 64;
    int n0l = N0 + lrow, n1l = N0 + 32 + lrow;
    long noff0 = (long)(n0l >> 6) * 64 + (n0l & 63);
    long noff1 = (long)(n1l >> 6) * 64 + (n1l & 63);
#pragma unroll
    for (int reg = 0; reg < 16; ++reg) {
        int row = (reg & 3) + 8 * (reg >> 2) + 4 * lq;
        int oc0 = O0 + row, oc1 = O0 + 32 + row;
        long cb0 = base0 + (long)(oc0 >> 6) * HWD + (long)(oc0 & 63) * 4096;
        long cb1 = base0 + (long)(oc1 >> 6) * HWD + (long)(oc1 & 63) * 4096;
        float bs0 = bias[oc0], bs1 = bias[oc1];
        Out[cb0 + noff0] = acc00[reg] + bs0;
        Out[cb0 + noff1] = acc01[reg] + bs0;
        Out[cb1 + noff0] = acc10[reg] + bs1;
        Out[cb1 + noff1] = acc11[reg] + bs1;
    }
}

// ---------------- attn: At[b,c,h,w2,d] = sum_w Cc[b,c,w2,h,w] * T[b,c,w2,w,d] (bf16 out) ----
__global__ void k_attn(const float* __restrict__ Cc, const float* __restrict__ T,
                       __hip_bfloat16* __restrict__ At) {
    __shared__ float As[64][65];
    __shared__ float Bs[64][64];
    int bc = blockIdx.x >> 6, w2 = blockIdx.x & 63;
    const float* Ap = Cc + ((long)bc * 64 + w2) * 4096;
    const float* Bp = T + ((long)bc * 64 + w2) * 4096;
    int t = threadIdx.x;
#pragma unroll
    for (int e0 = 0; e0 < 4096; e0 += 256) {
        int e = e0 + t;
        int r = e >> 6, q = e & 63;
        As[r][q] = Ap[e];
        Bs[r][q] = Bp[e];
    }
    __syncthreads();
    int h = t >> 2, dg = (t & 3) * 16;
    f32x16 acc = {0};
    for (int k = 0; k < 64; ++k) {
        float a = As[h][k];
#pragma unroll
        for (int i = 0; i < 16; ++i)
            acc[i] = fmaf(a, Bs[k][dg + i], acc[i]);
    }
    float tmp[16];
#pragma unroll
    for (int i = 0; i < 16; ++i) tmp[i] = acc[i];
    pack_row_bf16(At + (long)bc * HWD + (long)h * 4096 + w2 * 64 + dg, tmp);
}

// ---------------- f: F[b,c,h,w,d] = sum_w2 Cc[b,c,w2,h,w] * T[b,c,w2,w,d] (bf16 out) ----
// block = (bc, 8-wide w-tile), 512 threads; A staged with float4 (32B contiguous),
// B coalesced; Bs rows padded to 68. XCD swizzle keeps one bc on one XCD.
__global__ __launch_bounds__(512, 4) void k_f(const float* __restrict__ Cc,
        const float* __restrict__ T, __hip_bfloat16* __restrict__ F) {
    __shared__ float As[16][64][8];   // [kk][h][w]        32 KB
    __shared__ float Bs[16][8][68];   // [kk][w][d(+pad)]  34 KB
    int L = blockIdx.x;               // 1024 = 128 bc * 8 wt
    int xcd = L & 7, j = L >> 3;      // j 0..127
    int bc = xcd * 16 + (j >> 3), wt = j & 7;
    const float* Ab = Cc + (long)bc * HWD + wt * 8;
    const float* Bb = T + (long)bc * HWD + wt * 8 * 64;
    int t = threadIdx.x;
    int w = t & 7, h = t >> 3;
    f32x16 acc0 = {0}, acc1 = {0}, acc2 = {0}, acc3 = {0};

    for (int w2c = 0; w2c < 4; ++w2c) {
        __syncthreads();
        // A stage: 16 kk x 64 h x 2 half-float4 (32B contiguous per (kk,h))
#pragma unroll
        for (int i = 0; i < 4; ++i) {
            int f = i * 512 + t;                       // 0..2047
            int half = f & 1, hh = (f >> 1) & 63, kk = f >> 7;
            float4 v = *(const float4*)(Ab + (long)(w2c * 16 + kk) * 4096 + hh * 64 + half * 4);
            *(float4*)&As[kk][hh][half * 4] = v;
        }
        // B stage: 16 kk x 8 w x 16 float4 (256B contiguous per (kk,w))
#pragma unroll
        for (int i = 0; i < 4; ++i) {
            int f = i * 512 + t;
            int d4 = f & 15, ww = (f >> 4) & 7, kk = f >> 7;
            float4 v = *(const float4*)(Bb + (long)(w2c * 16 + kk) * 4096 + ww * 64 + d4 * 4);
            *(float4*)&Bs[kk][ww][d4 * 4] = v;
        }
        __syncthreads();
        for (int kk = 0; kk < 16; ++kk) {
            float a = As[kk][h][w];
            const float* br = &Bs[kk][w][0];
#pragma unroll
            for (int i = 0; i < 16; ++i) {
                acc0[i] = fmaf(a, br[i], acc0[i]);
                acc1[i] = fmaf(a, br[16 + i], acc1[i]);
                acc2[i] = fmaf(a, br[32 + i], acc2[i]);
                acc3[i] = fmaf(a, br[48 + i], acc3[i]);
            }
        }
    }
    // store: F[bc][h][wt*8+w][d], 128B per thread (contiguous)
    __hip_bfloat16* Fp = F + (long)bc * HWD + (long)h * 4096 + (wt * 8 + w) * 64;
    float tmp[16];
#pragma unroll
    for (int i = 0; i < 16; ++i) tmp[i] = acc0[i];
    pack_row_bf16(Fp, tmp);
#pragma unroll
    for (int i = 0; i < 16; ++i) tmp[i] = acc1[i];
    pack_row_bf16(Fp + 16, tmp);
#pragma unroll
    for (int i = 0; i < 16; ++i) tmp[i] = acc2[i];
    pack_row_bf16(Fp + 32, tmp);
#pragma unroll
    for (int i = 0; i < 16; ++i) tmp[i] = acc3[i];
    pack_row_bf16(Fp + 48, tmp);
}

// ---------------- map v4 (MFMA): out[n][c] = gelu( sum_k P[n][k] Wb[k][c] + b_map[c] ) ----
// P[n][k<64] = bf16(x[n][k] * F[k][n]),  P[n][k>=64] = At[k-64][n].
// Per 256-n block: 8 chunks of 16 k. Each chunk: stage x/F-or-At (same proven coalesced
// staging as v3) -> each thread packs its own P row (2 ds_write_b128) -> one
// 32x32x16 MFMA K-step per chunk into 4 accs/wave (64n x 64c). W: 16KB bf16 LDS tile.
// Replaces 8192 scalar FMAs/thread (55us VALU floor, measured 269us at 36% VALUBusy)
// with 32 MFMAs/wave; new floor is memory: 402MB ~ 70us.
__global__ __launch_bounds__(256, 4) void k_map(const float* __restrict__ x,
        const __hip_bfloat16* __restrict__ F, const __hip_bfloat16* __restrict__ At,
        const __hip_bfloat16* __restrict__ Wb, const float* __restrict__ b_map,
        float* __restrict__ out) {
    __shared__ float xs[16][257];             // 16448 B, col read (k2+t)%32 conflict-free
    __shared__ __hip_bfloat16 fa[16][264];    //  8448 B, F or At chunk
    __shared__ short Pl[256][24];             // 12288 B, 16 k bf16 + 8 pad (16B-aligned units)
    __shared__ short Wt[64][136];             // 17408 B, [c][k 128 + 8 pad]

    int t = threadIdx.x;
    long n0 = (long)blockIdx.x * 256;
    int b = (int)(n0 >> 18);
    long nn0 = n0 & (HWD - 1);
    const float* xblk = x + n0 * 64;
    const __hip_bfloat16* Fb = F + (long)b * 64 * HWD + nn0;
    const __hip_bfloat16* Ab = At + (long)b * 64 * HWD + nn0;

    // load W tile once: Wb[c][k] 64x128 bf16
#pragma unroll
    for (int i = 0; i < 4; ++i) {
        int e = i * 256 + t;                  // uint4 index, 1024 total
        int c = e >> 4, kk = (e & 15) * 8;
        *(uint4*)&Wt[c][kk] = *(const uint4*)((const short*)Wb + c * 128 + kk);
    }

    int lane = t & 63, wv = t >> 6;
    int lrow = lane & 31, lhalf = lane >> 5;
    f32x16 acc00 = {0}, acc01 = {0}, acc10 = {0}, acc11 = {0};

    for (int kc = 0; kc < 8; ++kc) {
        __syncthreads();   // prev chunk's Pl/xs/fa readers done; covers Wt load at kc=0
        if (kc < 4) {
            // stage x chunk: each 64B line fetched by one float4 instruction
#pragma unroll
            for (int i2 = 0; i2 < 4; ++i2) {
                int f = i2 * 256 + t;
                int nr = f >> 2, j4 = (f & 3) * 4;
                float4 v = *(const float4*)(xblk + nr * 64 + kc * 16 + j4);
                xs[j4 + 0][nr] = v.x;
                xs[j4 + 1][nr] = v.y;
                xs[j4 + 2][nr] = v.z;
                xs[j4 + 3][nr] = v.w;
            }
            // stage F chunk: 16 ch x 512B, uint4, fully coalesced
#pragma unroll
            for (int it = 0; it < 2; ++it) {
                int idx = it * 256 + t;
                int row = idx >> 5, seg = idx & 31;
                *(uint4*)&fa[row][seg * 8] =
                    *(const uint4*)(Fb + (long)(kc * 16 + row) * HWD + seg * 8);
            }
        } else {
            // stage At chunk
#pragma unroll
            for (int it = 0; it < 2; ++it) {
                int idx = it * 256 + t;
                int row = idx >> 5, seg = idx & 31;
                *(uint4*)&fa[row][seg * 8] =
                    *(const uint4*)(Ab + (long)((kc - 4) * 16 + row) * HWD + seg * 8);
            }
        }
        __syncthreads();
        // build P row t (16 bf16), write as 2x16B
        unsigned short pv[16];
        if (kc < 4) {
#pragma unroll
            for (int k2 = 0; k2 < 16; ++k2) {
                float p = xs[k2][t] * __bfloat162float(fa[k2][t]);
                __hip_bfloat16 h = __float2bfloat16(p);
                pv[k2] = *reinterpret_cast<unsigned short*>(&h);
            }
        } else {
#pragma unroll
            for (int k2 = 0; k2 < 16; ++k2)
                pv[k2] = *reinterpret_cast<const unsigned short*>(&fa[k2][t]);
        }
        *(uint4*)&Pl[t][0] = *(uint4*)&pv[0];
        *(uint4*)&Pl[t][8] = *(uint4*)&pv[8];
        __syncthreads();
        // MFMA K-step: A = P rows (n), B = Wt rows (c)
        bf16x8 a0 = *(const bf16x8*)&Pl[wv * 64 + lrow][lhalf * 8];
        bf16x8 a1 = *(const bf16x8*)&Pl[wv * 64 + 32 + lrow][lhalf * 8];
        bf16x8 b0 = *(const bf16x8*)&Wt[lrow][kc * 16 + lhalf * 8];
        bf16x8 b1 = *(const bf16x8*)&Wt[32 + lrow][kc * 16 + lhalf * 8];
        acc00 = __builtin_amdgcn_mfma_f32_32x32x16_bf16(a0, b0, acc00, 0, 0, 0);
        acc01 = __builtin_amdgcn_mfma_f32_32x32x16_bf16(a0, b1, acc01, 0, 0, 0);
        acc10 = __builtin_amdgcn_mfma_f32_32x32x16_bf16(a1, b0, acc10, 0, 0, 0);
        acc11 = __builtin_amdgcn_mfma_f32_32x32x16_bf16(a1, b1, acc11, 0, 0, 0);
    }

    // epilogue: bias + exact GELU + store.
    // D layout: col(c) = lane&31, row(n) = (reg&3)+8*(reg>>2)+4*lhalf
    float bs0 = b_map[lrow];
    float bs1 = b_map[32 + lrow];
    const float inv_sqrt2 = 0.70710678118654752440f;
    float* ob = out + (n0 + wv * 64) * 64;
#pragma unroll
    for (int reg = 0; reg < 16; ++reg) {
        int nrow = (reg & 3) + 8 * (reg >> 2) + 4 * lhalf;
        float v00 = acc00[reg] + bs0;
        float v01 = acc01[reg] + bs1;
        float v10 = acc10[reg] + bs0;
        float v11 = acc11[reg] + bs1;
        v00 = 0.5f * v00 * (1.f + erff(v00 * inv_sqrt2));
        v01 = 0.5f * v01 * (1.f + erff(v01 * inv_sqrt2));
        v10 = 0.5f * v10 * (1.f + erff(v10 * inv_sqrt2));
        v11 = 0.5f * v11 * (1.f + erff(v11 * inv_sqrt2));
        ob[(long)nrow * 64 + lrow] = v00;            // lanes 0-31 + 32-63: 2x128B contig
        ob[(long)nrow * 64 + 32 + lrow] = v01;
        ob[(long)(32 + nrow) * 64 + lrow] = v10;
        ob[(long)(32 + nrow) * 64 + 32 + lrow] = v11;
    }
}

extern "C" void kernel_launch(void* const* d_in, const int* in_sizes, int n_in,
                              void* d_out, int out_size, void* d_ws, size_t ws_size,
                              hipStream_t stream) {
    const float* x     = (const float*)d_in[0];
    const float* w_t   = (const float*)d_in[1];
    const float* b_t   = (const float*)d_in[2];
    const float* w_c   = (const float*)d_in[3];
    const float* b_c   = (const float*)d_in[4];
    const float* w_map = (const float*)d_in[5];
    const float* b_map = (const float*)d_in[6];
    float* out = (float*)d_out;
    float* ws = (float*)d_ws;

    // ws layout (float offsets), ~269 MB total:
    //  [0,        16777216)  Xc bf16  (33.5M elem)  -> reused as At bf16 after conv_c
    //  [16777216, 33554432)  Xt bf16                -> reused as F bf16 after conv_t
    //  [33554432, 67108864)  T fp32
    //  [67108864, ...)       A_t bf16 (147456) | A_c bf16 (147456) | Wb bf16 (8192)
    __hip_bfloat16* Xc = (__hip_bfloat16*)ws;
    __hip_bfloat16* Xt = (__hip_bfloat16*)(ws + 16777216L);
    float* T = ws + 33554432L;
    float* Cc = out;                                     // d_out as scratch
    __hip_bfloat16* A_t = (__hip_bfloat16*)(ws + 67108864L);
    __hip_bfloat16* A_c = (__hip_bfloat16*)(ws + 67182592L);
    __hip_bfloat16* Wb = (__hip_bfloat16*)(ws + 67256320L);
    __hip_bfloat16* At_bf = Xc;                          // 67 MB, Xc dead after convs
    __hip_bfloat16* F_bf = Xt;                           // 67 MB, Xt dead after convs

    hipLaunchKernelGGL(k_prep, dim3(576), dim3(256), 0, stream, w_t, w_c, w_map, A_t, A_c, Wb);
    hipLaunchKernelGGL(k_trans_c, dim3(4096, 2), dim3(256), 0, stream, x, Xc);
    hipLaunchKernelGGL(k_trans_t, dim3(4096, 2), dim3(256), 0, stream, x, Xt);
    hipLaunchKernelGGL(k_conv_mfma, dim3(2048), dim3(256), 0, stream, Xt, A_t, b_t, T);
    hipLaunchKernelGGL(k_conv_mfma, dim3(2048), dim3(256), 0, stream, Xc, A_c, b_c, Cc);
    hipLaunchKernelGGL(k_attn, dim3(8192), dim3(256), 0, stream, Cc, T, At_bf);
    hipLaunchKernelGGL(k_f, dim3(1024), dim3(512), 0, stream, Cc, T, F_bf);
    hipLaunchKernelGGL(k_map, dim3(2048), dim3(256), 0, stream, x, F_bf, At_bf, Wb, b_map, out);
}